// Round 12
// baseline (316.156 us; speedup 1.0000x reference)
//
#include <hip/hip_runtime.h>

typedef unsigned short u16;
typedef unsigned int u32;

#define B_ 4
#define N_ 256
#define T_ 36
#define C_ 64
#define H_ 4
#define D_ 16
#define CH_ 128
#define E_ 4096
#define EQ_ 1408   // per-quarter edge cap (mean 1024, sigma ~28 -> +14 sigma)
#define G_ (B_*T_)
#define TOK_ (B_*N_*T_)

// workspace layout (float offsets)
#define DS_OFF  0
#define XG_OFF  (DS_OFF + N_*C_)
#define HA_OFF  (XG_OFF + TOK_*C_)          // bf16 h buffer A (conv outs)
#define HB_OFF  (HA_OFF + G_*N_*CH_/2)      // bf16 buffer B (h1)
#define HS_OFF  (HB_OFF + G_*N_*CH_/2)
#define HD_OFF  (HS_OFF + G_*N_)
#define INT_OFF (HD_OFF + G_*N_)
#define MS_OFF  (INT_OFF + 4608)            // (m, 1/S) pairs: 576 * 512 floats
#define O_SEP_OFF (MS_OFF + 576*512)        // separate o_ws region (if ws permits)

__device__ __forceinline__ float bf2f(u16 u){
  u32 x = ((u32)u) << 16;
  return __builtin_bit_cast(float, x);
}
__device__ __forceinline__ u16 f2bf(float f){
  u32 x = __builtin_bit_cast(u32, f);
  x += 0x7fffu + ((x >> 16) & 1u);
  return (u16)(x >> 16);
}
__device__ __forceinline__ void unpack8(uint4 u, float* f){
  f[0]=bf2f((u16)(u.x & 0xffffu)); f[1]=bf2f((u16)(u.x >> 16));
  f[2]=bf2f((u16)(u.y & 0xffffu)); f[3]=bf2f((u16)(u.y >> 16));
  f[4]=bf2f((u16)(u.z & 0xffffu)); f[5]=bf2f((u16)(u.z >> 16));
  f[6]=bf2f((u16)(u.w & 0xffffu)); f[7]=bf2f((u16)(u.w >> 16));
}
__device__ __forceinline__ uint4 pack8f(const float* f){
  uint4 u;
  u.x = (u32)f2bf(f[0]) | ((u32)f2bf(f[1]) << 16);
  u.y = (u32)f2bf(f[2]) | ((u32)f2bf(f[3]) << 16);
  u.z = (u32)f2bf(f[4]) | ((u32)f2bf(f[5]) << 16);
  u.w = (u32)f2bf(f[6]) | ((u32)f2bf(f[7]) << 16);
  return u;
}
__device__ __forceinline__ int rfl(int v){ return __builtin_amdgcn_readfirstlane(v); }

// XCD swizzle: all 4 quarter-blocks of graph g share bid%8 == g%8 (same XCD L2)
__device__ __forceinline__ void gq_from_bid(int bid, int& g, int& q){
  int xc = bid & 7, slot = bid >> 3;
  q = slot & 3;
  g = xc + ((slot >> 2) << 3);
}

#define SP_ 20   // f32 attn row pitch (80B, 16B-aligned)

// parallel per-dst edge softmax: 4 threads per dst (slices mod 4), shfl-combined.
__device__ __forceinline__ void edge_softmax_par(int tid, int n0,
    const int* __restrict__ indptr, int p00,
    const int* srcs_l, const float* hs_l, const float* __restrict__ hd_ws,
    int g, float* alpha_l)
{
  const int ld = tid >> 2;
  const int sl = tid & 3;
  const int dst = n0 + ld;
  const int p0 = indptr[dst] - p00, p1 = indptr[dst+1] - p00;
  const float hdn = hd_ws[g*N_ + dst];
  float m = -1e30f;
  for (int j = p0 + sl; j < p1; j += 4){
    float e = hs_l[srcs_l[j]] + hdn;
    e = e > 0.f ? e : 0.2f * e;
    alpha_l[j] = e;
    m = fmaxf(m, e);
  }
  m = fmaxf(m, __shfl_xor(m, 1, 64));
  m = fmaxf(m, __shfl_xor(m, 2, 64));
  float s = 0.f;
  for (int j = p0 + sl; j < p1; j += 4){
    float w = __expf(alpha_l[j] - m);
    alpha_l[j] = w; s += w;
  }
  s += __shfl_xor(s, 1, 64);
  s += __shfl_xor(s, 2, 64);
  float inv = 1.f / (s + 1e-16f);
  for (int j = p0 + sl; j < p1; j += 4) alpha_l[j] *= inv;
}

// software-pipelined gather: acc[32] += alpha[j] * h[src[j]][ch0..ch0+32)
__device__ __forceinline__ void gather_pipelined(
    const u16* __restrict__ hin, int gN, int ch0,
    const int* srcs_l, const float* alpha_l, int p0, int p1, float* acc)
{
  uint4 c0v, c1v, c2v, c3v;
  float aC = 0.f;
  if (p0 < p1){
    int s = srcs_l[p0];
    const uint4* hp = (const uint4*)(hin + ((size_t)(gN + s))*CH_ + ch0);
    c0v = hp[0]; c1v = hp[1]; c2v = hp[2]; c3v = hp[3];
    aC = alpha_l[p0];
  }
  for (int j = p0; j < p1; j++){
    uint4 n0v = c0v, n1v = c1v, n2v = c2v, n3v = c3v;
    float aN = aC;
    if (j + 1 < p1){
      int s = srcs_l[j+1];
      const uint4* hp = (const uint4*)(hin + ((size_t)(gN + s))*CH_ + ch0);
      n0v = hp[0]; n1v = hp[1]; n2v = hp[2]; n3v = hp[3];
      aN = alpha_l[j+1];
    }
    float hv[8];
    unpack8(c0v, hv);
    #pragma unroll
    for (int i = 0; i < 8; i++) acc[i] += aC * hv[i];
    unpack8(c1v, hv);
    #pragma unroll
    for (int i = 0; i < 8; i++) acc[8+i] += aC * hv[i];
    unpack8(c2v, hv);
    #pragma unroll
    for (int i = 0; i < 8; i++) acc[16+i] += aC * hv[i];
    unpack8(c3v, hv);
    #pragma unroll
    for (int i = 0; i < 8; i++) acc[24+i] += aC * hv[i];
    c0v = n0v; c1v = n1v; c2v = n2v; c3v = n3v; aC = aN;
  }
}

// ---------------- fused pre: lin1 (576) + ds (64) + csr (1) ----------------
__global__ __launch_bounds__(256)
void k_pre(const float* __restrict__ query, const float* __restrict__ W1,
           const float* __restrict__ as1, const float* __restrict__ ad1,
           u16* __restrict__ h, float* __restrict__ hs_ws, float* __restrict__ hd_ws,
           const float* __restrict__ DSm, const float* __restrict__ Wemb,
           const float* __restrict__ bemb, float* __restrict__ dsb,
           const int* __restrict__ ei, int* __restrict__ indptr, int* __restrict__ srcs)
{
  __shared__ union UP {
    struct { float xs[64][65]; float red[2][4][64]; } lin;
    struct { int srcL[E_]; int dstL[E_]; int tmp[E_]; int cnt[N_]; int base[N_+1]; } c;
  } S;
  const int bid = blockIdx.x;
  const int tid = threadIdx.x;

  if (bid < 576){
    int g, q; gq_from_bid(bid, g, q);
    const int n0 = q * 64;
    const int b = g / T_, t = g % T_;
    {
      const size_t gb = (((size_t)b*N_ + n0)*T_ + t)*C_;
      #pragma unroll
      for (int it = 0; it < 4; it++){
        int idx = tid + 256*it;
        int row = idx >> 4, c4 = (idx & 15) * 4;
        float4 v = *(const float4*)(query + gb + (size_t)row*(T_*C_) + c4);
        S.lin.xs[row][c4+0] = v.x; S.lin.xs[row][c4+1] = v.y;
        S.lin.xs[row][c4+2] = v.z; S.lin.xs[row][c4+3] = v.w;
      }
    }
    __syncthreads();

    const int r = tid & 63;
    const int cb = rfl(tid >> 6);
    const int ch0 = cb * 32;

    float acc[32];
    #pragma unroll
    for (int j = 0; j < 32; j++) acc[j] = 0.f;
    for (int k = 0; k < 64; k++){
      float xv = S.lin.xs[r][k];
      const float* wrow = W1 + k*CH_ + ch0;   // wave-uniform -> scalar loads
      #pragma unroll
      for (int j = 0; j < 32; j++) acc[j] += xv * wrow[j];
    }
    float hs = 0.f, hd = 0.f;
    #pragma unroll
    for (int j = 0; j < 32; j++){ hs += acc[j]*as1[ch0+j]; hd += acc[j]*ad1[ch0+j]; }
    S.lin.red[0][cb][r] = hs; S.lin.red[1][cb][r] = hd;

    u16* hp = h + ((size_t)(g*N_ + n0 + r))*CH_ + ch0;
    #pragma unroll
    for (int j8 = 0; j8 < 32; j8 += 8)
      *(uint4*)(hp + j8) = pack8f(&acc[j8]);

    __syncthreads();
    if (tid < 64){
      float a = S.lin.red[0][0][tid]+S.lin.red[0][1][tid]+S.lin.red[0][2][tid]+S.lin.red[0][3][tid];
      float d = S.lin.red[1][0][tid]+S.lin.red[1][1][tid]+S.lin.red[1][2][tid]+S.lin.red[1][3][tid];
      hs_ws[g*N_ + n0 + tid] = a;
      hd_ws[g*N_ + n0 + tid] = d;
    }
  } else if (bid < 640){
    const int n = (bid - 576) * 4 + (tid >> 6);   // wave-uniform
    const int c = tid & 63;
    float acc = bemb[c];
    for (int m = 0; m < N_; m++) acc += DSm[n*N_ + m] * Wemb[m*C_ + c];
    dsb[n*C_ + c] = acc;
  } else {
    for (int e = tid; e < E_; e += 256){ S.c.srcL[e] = ei[e]; S.c.dstL[e] = ei[E_ + e]; }
    S.c.cnt[tid] = 0;
    __syncthreads();
    for (int e = tid; e < E_; e += 256) atomicAdd(&S.c.cnt[S.c.dstL[e]], 1);
    __syncthreads();
    if (tid == 0){
      int run = 0;
      for (int i = 0; i < N_; i++){ S.c.base[i] = run; run += S.c.cnt[i]; }
      S.c.base[N_] = run;
    }
    __syncthreads();
    S.c.cnt[tid] = 0;
    __syncthreads();
    for (int e = tid; e < E_; e += 256){
      int d = S.c.dstL[e];
      int p = atomicAdd(&S.c.cnt[d], 1);
      S.c.tmp[S.c.base[d] + p] = e;
    }
    __syncthreads();
    {
      const int p0 = S.c.base[tid], p1 = S.c.base[tid] + S.c.cnt[tid];
      for (int i = p0 + 1; i < p1; i++){      // insertion sort by edge id -> deterministic
        int v = S.c.tmp[i]; int j = i - 1;
        while (j >= p0 && S.c.tmp[j] > v){ S.c.tmp[j+1] = S.c.tmp[j]; j--; }
        S.c.tmp[j+1] = v;
      }
      for (int j = p0; j < p1; j++) srcs[j] = S.c.srcL[S.c.tmp[j]];
    }
    indptr[tid] = S.c.base[tid];
    if (tid == 0) indptr[N_] = S.c.base[N_];
  }
}

// ---------------- K2: agg1 (blocks 0..575) ∥ attn stats (576..1151) ----------------
__global__ __launch_bounds__(256)
void k_agg1stat(const u16* __restrict__ hin, const float* __restrict__ hs_ws, const float* __restrict__ hd_ws,
                const int* __restrict__ indptr, const int* __restrict__ srcs,
                const float* __restrict__ bias, u16* __restrict__ hout,
                const float* __restrict__ query, const float* __restrict__ key,
                const float* __restrict__ Wq, const float* __restrict__ Wk,
                const float* __restrict__ dsb, float* __restrict__ mS)
{
  __shared__ union UA {
    struct { int srcs_l[EQ_]; float alpha_l[EQ_]; float hs_l[N_]; } a;
    struct { float qs[N_][SP_]; float wq[16][16]; float wk[16][16]; } s;
  } U;
  const int bid = blockIdx.x;
  const int tid = threadIdx.x;

  if (bid < 576){
    int g, q; gq_from_bid(bid, g, q);
    const int n0 = q * 64;

    const int p00 = indptr[n0];
    const int pend = indptr[n0 + 64];
    const int cntE = pend - p00;
    for (int i = tid; i < cntE; i += 256) U.a.srcs_l[i] = srcs[p00 + i];
    U.a.hs_l[tid] = hs_ws[g*N_ + tid];
    __syncthreads();

    edge_softmax_par(tid, n0, indptr, p00, U.a.srcs_l, U.a.hs_l, hd_ws, g, U.a.alpha_l);
    __syncthreads();

    const int r = tid & 63;
    const int cb = rfl(tid >> 6);
    const int ch0 = cb * 32;
    const int dst = n0 + r;
    const int p0 = indptr[dst] - p00, p1 = indptr[dst+1] - p00;

    float acc[32];
    #pragma unroll
    for (int j = 0; j < 32; j++) acc[j] = 0.f;
    gather_pipelined(hin, g*N_, ch0, U.a.srcs_l, U.a.alpha_l, p0, p1, acc);

    float o[32];
    #pragma unroll
    for (int j = 0; j < 32; j++){
      float v = acc[j] + bias[ch0+j];
      o[j] = v > 0.f ? v : 0.f;
    }
    u16* op = hout + ((size_t)(g*N_ + dst))*CH_ + ch0;
    #pragma unroll
    for (int j8 = 0; j8 < 32; j8 += 8)
      *(uint4*)(op + j8) = pack8f(&o[j8]);
  } else {
    // attn stats: per (b,t,h), thread = column k; (m, 1/S) over q axis
    const int sb = bid - 576;
    const int b = sb / (T_*H_);
    const int rem = sb % (T_*H_);
    const int t = rem / H_;
    const int h = rem % H_;
    const int n = tid;

    U.s.wq[n>>4][n&15] = Wq[n];
    U.s.wk[n>>4][n&15] = Wk[n];

    const size_t base = ((((size_t)b*N_ + n)*T_) + t)*C_ + h*D_;
    const float* dsp = dsb + n*C_ + h*D_;

    float x[16];
    #pragma unroll
    for (int j4 = 0; j4 < 16; j4 += 4){
      float4 a = *(const float4*)(query + base + j4);
      float4 d = *(const float4*)(dsp + j4);
      x[j4]=a.x+d.x; x[j4+1]=a.y+d.y; x[j4+2]=a.z+d.z; x[j4+3]=a.w+d.w;
    }
    __syncthreads();   // weights staged
    #pragma unroll
    for (int j = 0; j < 16; j++){
      float a = 0.f;
      #pragma unroll
      for (int i = 0; i < 16; i++) a += x[i]*U.s.wq[i][j];
      U.s.qs[n][j] = a;
    }
    float khr[16];
    #pragma unroll
    for (int j4 = 0; j4 < 16; j4 += 4){
      float4 a = *(const float4*)(key + base + j4);
      float4 d = *(const float4*)(dsp + j4);
      x[j4]=a.x+d.x; x[j4+1]=a.y+d.y; x[j4+2]=a.z+d.z; x[j4+3]=a.w+d.w;
    }
    #pragma unroll
    for (int j = 0; j < 16; j++){
      float a = 0.f;
      #pragma unroll
      for (int i = 0; i < 16; i++) a += x[i]*U.s.wk[i][j];
      khr[j] = a;
    }
    __syncthreads();   // qs complete

    float m[4], s[4];
    #pragma unroll
    for (int c = 0; c < 4; c++){ m[c] = -1e30f; s[c] = 0.f; }
    for (int qq = 0; qq < 64; qq++){
      #pragma unroll
      for (int c = 0; c < 4; c++){
        const float* qrow = &U.s.qs[qq + 64*c][0];
        float4 a0 = *(const float4*)(qrow);
        float4 a1 = *(const float4*)(qrow+4);
        float4 a2 = *(const float4*)(qrow+8);
        float4 a3 = *(const float4*)(qrow+12);
        float d = a0.x*khr[0]+a0.y*khr[1]+a0.z*khr[2]+a0.w*khr[3]
                + a1.x*khr[4]+a1.y*khr[5]+a1.z*khr[6]+a1.w*khr[7]
                + a2.x*khr[8]+a2.y*khr[9]+a2.z*khr[10]+a2.w*khr[11]
                + a3.x*khr[12]+a3.y*khr[13]+a3.z*khr[14]+a3.w*khr[15];
        d *= 0.125f;
        float mn = fmaxf(m[c], d);
        s[c] = s[c]*__expf(m[c]-mn) + __expf(d-mn);
        m[c] = mn;
      }
    }
    float M = fmaxf(fmaxf(m[0],m[1]), fmaxf(m[2],m[3]));
    float S = s[0]*__expf(m[0]-M) + s[1]*__expf(m[1]-M)
            + s[2]*__expf(m[2]-M) + s[3]*__expf(m[3]-M);
    mS[(size_t)sb*512 + n*2]     = M;
    mS[(size_t)sb*512 + n*2 + 1] = 1.f / S;
  }
}

// ---------------- lin2: h2 = bf16(h1 @ W2), fused hs2/hd2 ----------------
__global__ __launch_bounds__(256)
void k_lin2(const u16* __restrict__ h1, const float* __restrict__ W2,
            const float* __restrict__ as2, const float* __restrict__ ad2,
            u16* __restrict__ h2, float* __restrict__ hs_ws, float* __restrict__ hd_ws)
{
  __shared__ float xs[64][129];
  __shared__ float red[2][4][64];
  const int bid = blockIdx.x;
  int g, q; gq_from_bid(bid, g, q);
  const int n0 = q * 64;
  const int tid = threadIdx.x;

  {
    #pragma unroll
    for (int it = 0; it < 4; it++){
      int idx = tid + 256*it;
      int row = idx >> 4, c8 = (idx & 15) * 8;
      uint4 u = *(const uint4*)(h1 + ((size_t)(g*N_ + n0 + row))*CH_ + c8);
      float v[8]; unpack8(u, v);
      #pragma unroll
      for (int i = 0; i < 8; i++) xs[row][c8+i] = v[i];
    }
  }
  __syncthreads();

  const int r = tid & 63;
  const int cb = rfl(tid >> 6);
  const int ch0 = cb * 32;

  float acc[32];
  #pragma unroll
  for (int j = 0; j < 32; j++) acc[j] = 0.f;
  for (int k = 0; k < 128; k++){
    float xv = xs[r][k];
    const float* wrow = W2 + k*CH_ + ch0;
    #pragma unroll
    for (int j = 0; j < 32; j++) acc[j] += xv * wrow[j];
  }
  float hs = 0.f, hd = 0.f;
  #pragma unroll
  for (int j = 0; j < 32; j++){ hs += acc[j]*as2[ch0+j]; hd += acc[j]*ad2[ch0+j]; }
  red[0][cb][r] = hs; red[1][cb][r] = hd;

  u16* hp = h2 + ((size_t)(g*N_ + n0 + r))*CH_ + ch0;
  #pragma unroll
  for (int j8 = 0; j8 < 32; j8 += 8)
    *(uint4*)(hp + j8) = pack8f(&acc[j8]);

  __syncthreads();
  if (tid < 64){
    float a = red[0][0][tid]+red[0][1][tid]+red[0][2][tid]+red[0][3][tid];
    float d = red[1][0][tid]+red[1][1][tid]+red[1][2][tid]+red[1][3][tid];
    hs_ws[g*N_ + n0 + tid] = a;
    hd_ws[g*N_ + n0 + tid] = d;
  }
}

// ---------------- K4: agg2+jk (eff 0..575) ∥ attn AV (eff 576..1151) ----------------
__global__ __launch_bounds__(256)
void k_agg2av(const u16* __restrict__ h2, const float* __restrict__ hs_ws, const float* __restrict__ hd_ws,
              const int* __restrict__ indptr, const int* __restrict__ srcs,
              const float* __restrict__ b2, const u16* __restrict__ h1,
              const float* __restrict__ jkW, const float* __restrict__ jkb, float* __restrict__ xg,
              const float* __restrict__ query, const float* __restrict__ key, const float* __restrict__ value,
              const float* __restrict__ Wq, const float* __restrict__ Wk, const float* __restrict__ Wv,
              const float* __restrict__ dsb, const float* __restrict__ mS, float* __restrict__ o_ws,
              int bid_base)
{
  __shared__ union UJ {
    struct { int srcs_l[EQ_]; float alpha_l[EQ_]; float hs_l[N_]; } a;
    struct { u16 xs[64][136]; } l;
    struct { u16 ks[N_][16]; u16 vs[N_][16]; float2 msl[N_];
             float wq[16][16]; float wk[16][16]; float wv[16][16]; } v;
  } U;
  const int bid = blockIdx.x + bid_base;
  const int tid = threadIdx.x;

  if (bid < 576){
    int g, q; gq_from_bid(bid, g, q);
    const int n0 = q * 64;
    const int b = g / T_, t = g % T_;

    // ---- agg2 (output stays in regs) ----
    const int p00 = indptr[n0];
    const int pend = indptr[n0 + 64];
    const int cntE = pend - p00;
    for (int i = tid; i < cntE; i += 256) U.a.srcs_l[i] = srcs[p00 + i];
    U.a.hs_l[tid] = hs_ws[g*N_ + tid];
    __syncthreads();

    edge_softmax_par(tid, n0, indptr, p00, U.a.srcs_l, U.a.hs_l, hd_ws, g, U.a.alpha_l);
    __syncthreads();

    const int r = tid & 63;
    const int cb = rfl(tid >> 6);
    const int ch0 = cb * 32;
    const int dst = n0 + r;
    const int p0 = indptr[dst] - p00, p1 = indptr[dst+1] - p00;

    float acc[32];
    #pragma unroll
    for (int j = 0; j < 32; j++) acc[j] = 0.f;
    gather_pipelined(h2, g*N_, ch0, U.a.srcs_l, U.a.alpha_l, p0, p1, acc);

    float o[32];
    {
      const uint4* h1p = (const uint4*)(h1 + ((size_t)(g*N_ + dst))*CH_ + ch0);
      #pragma unroll
      for (int j8 = 0; j8 < 32; j8 += 8){
        float h1v[8]; unpack8(h1p[j8>>3], h1v);
        #pragma unroll
        for (int i = 0; i < 8; i++){
          float v = acc[j8+i] + b2[ch0+j8+i];
          v = v > 0.f ? v : 0.f;
          o[j8+i] = fmaxf(h1v[i], v);
        }
      }
    }
    __syncthreads();   // all agg reads of U.a done

    // regs -> xs (bf16)
    #pragma unroll
    for (int j8 = 0; j8 < 32; j8 += 8)
      *(uint4*)&U.l.xs[r][ch0 + j8] = pack8f(&o[j8]);
    __syncthreads();

    // jk linear: xg(time-reversed) = xs @ jkW + jkb
    const int o0 = cb * 16;
    float acc2[16];
    #pragma unroll
    for (int j = 0; j < 16; j++) acc2[j] = 0.f;
    for (int k8 = 0; k8 < 16; k8++){
      uint4 u = *(const uint4*)&U.l.xs[r][k8*8];
      float hv[8]; unpack8(u, hv);
      #pragma unroll
      for (int kk = 0; kk < 8; kk++){
        const float* wrow = jkW + (k8*8+kk)*C_ + o0;
        #pragma unroll
        for (int j = 0; j < 16; j++) acc2[j] += hv[kk] * wrow[j];
      }
    }
    float* op = xg + ((((size_t)b*N_ + n0 + r)*T_) + (T_-1-t))*C_ + o0;
    #pragma unroll
    for (int j4 = 0; j4 < 16; j4 += 4){
      float4 v = make_float4(acc2[j4]+jkb[o0+j4], acc2[j4+1]+jkb[o0+j4+1],
                             acc2[j4+2]+jkb[o0+j4+2], acc2[j4+3]+jkb[o0+j4+3]);
      *(float4*)(op + j4) = v;
    }
  } else {
    // ---- attn AV: per (b,t,h), thread = row q; K/V staged bf16; stats precomputed ----
    const int sb = bid - 576;
    const int b = sb / (T_*H_);
    const int rem = sb % (T_*H_);
    const int t = rem / H_;
    const int h = rem % H_;
    const int n = tid;

    U.v.wq[n>>4][n&15] = Wq[n];
    U.v.wk[n>>4][n&15] = Wk[n];
    U.v.wv[n>>4][n&15] = Wv[n];
    U.v.msl[n] = *(const float2*)(mS + (size_t)sb*512 + n*2);

    const size_t base = ((((size_t)b*N_ + n)*T_) + t)*C_ + h*D_;
    const float* dsp = dsb + n*C_ + h*D_;

    float ds16[16];
    #pragma unroll
    for (int j4 = 0; j4 < 16; j4 += 4){
      float4 d = *(const float4*)(dsp + j4);
      ds16[j4]=d.x; ds16[j4+1]=d.y; ds16[j4+2]=d.z; ds16[j4+3]=d.w;
    }
    __syncthreads();   // weights staged

    float x[16], r0[16];
    #pragma unroll
    for (int j4 = 0; j4 < 16; j4 += 4){
      float4 a = *(const float4*)(key + base + j4);
      x[j4]=a.x+ds16[j4]; x[j4+1]=a.y+ds16[j4+1]; x[j4+2]=a.z+ds16[j4+2]; x[j4+3]=a.w+ds16[j4+3];
    }
    #pragma unroll
    for (int j = 0; j < 16; j++){
      float a = 0.f;
      #pragma unroll
      for (int i = 0; i < 16; i++) a += x[i]*U.v.wk[i][j];
      r0[j] = a;
    }
    *(uint4*)&U.v.ks[n][0] = pack8f(&r0[0]);
    *(uint4*)&U.v.ks[n][8] = pack8f(&r0[8]);

    #pragma unroll
    for (int j4 = 0; j4 < 16; j4 += 4){
      float4 a = *(const float4*)(value + base + j4);
      x[j4]=a.x+ds16[j4]; x[j4+1]=a.y+ds16[j4+1]; x[j4+2]=a.z+ds16[j4+2]; x[j4+3]=a.w+ds16[j4+3];
    }
    #pragma unroll
    for (int j = 0; j < 16; j++){
      float a = 0.f;
      #pragma unroll
      for (int i = 0; i < 16; i++) a += x[i]*U.v.wv[i][j];
      r0[j] = a;
    }
    *(uint4*)&U.v.vs[n][0] = pack8f(&r0[0]);
    *(uint4*)&U.v.vs[n][8] = pack8f(&r0[8]);

    float qhr[16];
    #pragma unroll
    for (int j4 = 0; j4 < 16; j4 += 4){
      float4 a = *(const float4*)(query + base + j4);
      x[j4]=a.x+ds16[j4]; x[j4+1]=a.y+ds16[j4+1]; x[j4+2]=a.z+ds16[j4+2]; x[j4+3]=a.w+ds16[j4+3];
    }
    #pragma unroll
    for (int j = 0; j < 16; j++){
      float a = 0.f;
      #pragma unroll
      for (int i = 0; i < 16; i++) a += x[i]*U.v.wq[i][j];
      qhr[j] = a;
    }
    __syncthreads();   // ks/vs/msl complete

    float o0[16], o1[16];
    #pragma unroll
    for (int j = 0; j < 16; j++){ o0[j] = 0.f; o1[j] = 0.f; }
    for (int k = 0; k < N_; k += 2){
      {
        uint4 u0 = *(const uint4*)&U.v.ks[k][0];
        uint4 u1 = *(const uint4*)&U.v.ks[k][8];
        float kv[16]; unpack8(u0, kv); unpack8(u1, kv+8);
        float d = kv[0]*qhr[0]+kv[1]*qhr[1]+kv[2]*qhr[2]+kv[3]*qhr[3]
                + kv[4]*qhr[4]+kv[5]*qhr[5]+kv[6]*qhr[6]+kv[7]*qhr[7]
                + kv[8]*qhr[8]+kv[9]*qhr[9]+kv[10]*qhr[10]+kv[11]*qhr[11]
                + kv[12]*qhr[12]+kv[13]*qhr[13]+kv[14]*qhr[14]+kv[15]*qhr[15];
        float2 ms0 = U.v.msl[k];
        float p = __expf(d*0.125f - ms0.x) * ms0.y;
        uint4 v0 = *(const uint4*)&U.v.vs[k][0];
        uint4 v1 = *(const uint4*)&U.v.vs[k][8];
        float vv[16]; unpack8(v0, vv); unpack8(v1, vv+8);
        #pragma unroll
        for (int j = 0; j < 16; j++) o0[j] += p * vv[j];
      }
      {
        uint4 u0 = *(const uint4*)&U.v.ks[k+1][0];
        uint4 u1 = *(const uint4*)&U.v.ks[k+1][8];
        float kv[16]; unpack8(u0, kv); unpack8(u1, kv+8);
        float d = kv[0]*qhr[0]+kv[1]*qhr[1]+kv[2]*qhr[2]+kv[3]*qhr[3]
                + kv[4]*qhr[4]+kv[5]*qhr[5]+kv[6]*qhr[6]+kv[7]*qhr[7]
                + kv[8]*qhr[8]+kv[9]*qhr[9]+kv[10]*qhr[10]+kv[11]*qhr[11]
                + kv[12]*qhr[12]+kv[13]*qhr[13]+kv[14]*qhr[14]+kv[15]*qhr[15];
        float2 ms1 = U.v.msl[k+1];
        float p = __expf(d*0.125f - ms1.x) * ms1.y;
        uint4 v0 = *(const uint4*)&U.v.vs[k+1][0];
        uint4 v1 = *(const uint4*)&U.v.vs[k+1][8];
        float vv[16]; unpack8(v0, vv); unpack8(v1, vv+8);
        #pragma unroll
        for (int j = 0; j < 16; j++) o1[j] += p * vv[j];
      }
    }
    float* op = o_ws + base;
    #pragma unroll
    for (int j4 = 0; j4 < 16; j4 += 4)
      *(float4*)(op + j4) = make_float4(o0[j4]+o1[j4], o0[j4+1]+o1[j4+1],
                                        o0[j4+2]+o1[j4+2], o0[j4+3]+o1[j4+3]);
  }
}

// ---------------- fused epilogue: bf16 LDS staging ----------------
__global__ __launch_bounds__(256)
void k_final(const float* __restrict__ query, const float* __restrict__ dsb,
             const float* __restrict__ o_ws, const float* __restrict__ xg_ws,
             const float* __restrict__ Wfc, const float* __restrict__ bfc,
             const float* __restrict__ ln1g, const float* __restrict__ ln1b,
             const float* __restrict__ ln2g, const float* __restrict__ ln2b,
             const float* __restrict__ Wff1, const float* __restrict__ bff1,
             const float* __restrict__ Wff2, const float* __restrict__ bff2,
             const float* __restrict__ Wfs, const float* __restrict__ bfs,
             const float* __restrict__ Wfg, const float* __restrict__ bfg,
             float* __restrict__ out)
{
  __shared__ u16 smA[64*66];                       // o_t -> us_t (bf16)
  __shared__ u16 smB[64*66];                       // qd_t -> ms_t (bf16)
  __shared__ union UH { u16 h[128*66]; float o[64*66]; } HH;  // hidden/xg (bf16) -> out_t (f32)
  __shared__ float lnxA[4][64];
  __shared__ float lnxB[4][64];

  const int tid = threadIdx.x;
  const int token0 = blockIdx.x * 64;
  const int w = rfl(tid >> 6);
  const int tok = tid & 63;
  const int c0 = w * 16;

  #pragma unroll
  for (int it = 0; it < 4; it++){
    int idx = tid + 256*it;
    int tk = idx >> 4, c4 = (idx & 15) * 4;
    int gtok = token0 + tk;
    int n = (gtok / T_) & (N_-1);
    float4 ov = *(const float4*)(o_ws + (size_t)gtok*C_ + c4);
    float4 qv = *(const float4*)(query + (size_t)gtok*C_ + c4);
    float4 dv = *(const float4*)(dsb + n*C_ + c4);
    smA[(c4+0)*66+tk] = f2bf(ov.x); smA[(c4+1)*66+tk] = f2bf(ov.y);
    smA[(c4+2)*66+tk] = f2bf(ov.z); smA[(c4+3)*66+tk] = f2bf(ov.w);
    smB[(c4+0)*66+tk] = f2bf(qv.x+dv.x); smB[(c4+1)*66+tk] = f2bf(qv.y+dv.y);
    smB[(c4+2)*66+tk] = f2bf(qv.z+dv.z); smB[(c4+3)*66+tk] = f2bf(qv.w+dv.w);
  }
  __syncthreads();

  // fc
  float x1[16];
  #pragma unroll
  for (int j = 0; j < 16; j++) x1[j] = 0.f;
  for (int i = 0; i < C_; i++){
    float ov = bf2f(smA[i*66 + tok]);
    const float* wrow = Wfc + i*C_ + c0;
    #pragma unroll
    for (int j = 0; j < 16; j++) x1[j] += ov * wrow[j];
  }
  #pragma unroll
  for (int j = 0; j < 16; j++) x1[j] += bfc[c0+j] + bf2f(smB[(c0+j)*66 + tok]);

  // LN1
  float s1 = 0.f;
  #pragma unroll
  for (int j = 0; j < 16; j++) s1 += x1[j];
  lnxA[w][tok] = s1;
  __syncthreads();
  float mu = (lnxA[0][tok]+lnxA[1][tok]+lnxA[2][tok]+lnxA[3][tok]) * (1.f/64.f);
  float v1 = 0.f;
  #pragma unroll
  for (int j = 0; j < 16; j++){ float d = x1[j]-mu; v1 += d*d; }
  lnxB[w][tok] = v1;
  __syncthreads();
  float var = (lnxB[0][tok]+lnxB[1][tok]+lnxB[2][tok]+lnxB[3][tok]) * (1.f/64.f);
  float rstd = rsqrtf(var + 1e-5f);
  float ms[16];
  #pragma unroll
  for (int j = 0; j < 16; j++) ms[j] = (x1[j]-mu)*rstd*ln1g[c0+j] + ln1b[c0+j];
  __syncthreads();
  #pragma unroll
  for (int j = 0; j < 16; j++) smB[(c0+j)*66 + tok] = f2bf(ms[j]);
  __syncthreads();

  // FFN
  float part[16];
  #pragma unroll
  for (int j = 0; j < 16; j++) part[j] = 0.f;
  #pragma unroll
  for (int ch = 0; ch < 2; ch++){
    float fch[32];
    #pragma unroll
    for (int kk = 0; kk < 32; kk++) fch[kk] = 0.f;
    const int kbase = w*64 + ch*32;
    for (int i = 0; i < C_; i++){
      float msv = bf2f(smB[i*66 + tok]);
      const float* wrow = Wff1 + i*(4*C_) + kbase;
      #pragma unroll
      for (int kk = 0; kk < 32; kk++) fch[kk] += msv * wrow[kk];
    }
    #pragma unroll
    for (int kk = 0; kk < 32; kk++){
      float v = fch[kk] + bff1[kbase+kk];
      fch[kk] = v > 0.f ? v : 0.f;
    }
    if (ch) __syncthreads();
    #pragma unroll
    for (int kk = 0; kk < 32; kk++) HH.h[(w*32+kk)*66 + tok] = f2bf(fch[kk]);
    __syncthreads();
    #pragma unroll
    for (int wq = 0; wq < 4; wq++){
      #pragma unroll 8
      for (int kk = 0; kk < 32; kk++){
        int k = wq*64 + ch*32 + kk;
        float hv = bf2f(HH.h[(wq*32+kk)*66 + tok]);
        const float* wrow = Wff2 + k*C_ + c0;
        #pragma unroll
        for (int j = 0; j < 16; j++) part[j] += hv * wrow[j];
      }
    }
  }
  float x2[16];
  #pragma unroll
  for (int j = 0; j < 16; j++) x2[j] = part[j] + bff2[c0+j] + ms[j];

  // LN2
  float s2 = 0.f;
  #pragma unroll
  for (int j = 0; j < 16; j++) s2 += x2[j];
  __syncthreads();
  lnxA[w][tok] = s2;
  __syncthreads();
  float mu2 = (lnxA[0][tok]+lnxA[1][tok]+lnxA[2][tok]+lnxA[3][tok]) * (1.f/64.f);
  float v2 = 0.f;
  #pragma unroll
  for (int j = 0; j < 16; j++){ float d = x2[j]-mu2; v2 += d*d; }
  lnxB[w][tok] = v2;
  __syncthreads();
  float var2 = (lnxB[0][tok]+lnxB[1][tok]+lnxB[2][tok]+lnxB[3][tok]) * (1.f/64.f);
  float rstd2 = rsqrtf(var2 + 1e-5f);
  float us[16];
  #pragma unroll
  for (int j = 0; j < 16; j++) us[j] = (x2[j]-mu2)*rstd2*ln2g[c0+j] + ln2b[c0+j];

  // us -> smA ; xg -> HH.h rows 0..63 (hidden dead)
  #pragma unroll
  for (int j = 0; j < 16; j++) smA[(c0+j)*66 + tok] = f2bf(us[j]);
  #pragma unroll
  for (int it = 0; it < 4; it++){
    int idx = tid + 256*it;
    int tk = idx >> 4, c4 = (idx & 15) * 4;
    int gtok = token0 + tk;
    float4 xv = *(const float4*)(xg_ws + (size_t)gtok*C_ + c4);
    HH.h[(c4+0)*66+tk] = f2bf(xv.x); HH.h[(c4+1)*66+tk] = f2bf(xv.y);
    HH.h[(c4+2)*66+tk] = f2bf(xv.z); HH.h[(c4+3)*66+tk] = f2bf(xv.w);
  }
  __syncthreads();

  // gate
  float ga[16];
  #pragma unroll
  for (int j = 0; j < 16; j++) ga[j] = 0.f;
  for (int i = 0; i < C_; i++){
    float uv = bf2f(smA[i*66 + tok]);
    float xv = bf2f(HH.h[i*66 + tok]);
    const float* wsr = Wfs + i*C_ + c0;
    const float* wgr = Wfg + i*C_ + c0;
    #pragma unroll
    for (int j = 0; j < 16; j++) ga[j] += uv*wsr[j] + xv*wgr[j];
  }
  float res[16];
  #pragma unroll
  for (int j = 0; j < 16; j++){
    float a = ga[j] + bfs[c0+j] + bfg[c0+j];
    float gg = 1.f / (1.f + __expf(-a));
    float xgv = bf2f(HH.h[(c0+j)*66 + tok]);
    res[j] = gg*us[j] + (1.f-gg)*xgv;
  }
  __syncthreads();   // all xg reads done before f32 reuse of HH
  #pragma unroll
  for (int j = 0; j < 16; j++) HH.o[(c0+j)*66 + tok] = res[j];
  __syncthreads();
  #pragma unroll
  for (int it = 0; it < 4; it++){
    int idx = tid + 256*it;
    int tk = idx >> 4, c4 = (idx & 15) * 4;
    int gtok = token0 + tk;
    float4 v = make_float4(HH.o[(c4+0)*66+tk], HH.o[(c4+1)*66+tk],
                           HH.o[(c4+2)*66+tk], HH.o[(c4+3)*66+tk]);
    *(float4*)(out + (size_t)gtok*C_ + c4) = v;
  }
}

extern "C" void kernel_launch(void* const* d_in, const int* in_sizes, int n_in,
                              void* d_out, int out_size, void* d_ws, size_t ws_size,
                              hipStream_t stream)
{
  (void)in_sizes; (void)n_in; (void)out_size;
  const float* query = (const float*)d_in[0];
  const float* key   = (const float*)d_in[1];
  const float* value = (const float*)d_in[2];
  const float* DSm   = (const float*)d_in[4];
  const float* Wemb  = (const float*)d_in[5];
  const float* bemb  = (const float*)d_in[6];
  const float* Wq    = (const float*)d_in[7];
  const float* Wk    = (const float*)d_in[8];
  const float* Wv    = (const float*)d_in[9];
  const float* Wfc   = (const float*)d_in[10];
  const float* bfc   = (const float*)d_in[11];
  const float* ln1g  = (const float*)d_in[12];
  const float* ln1b  = (const float*)d_in[13];
  const float* ln2g  = (const float*)d_in[14];
  const float* ln2b  = (const float*)d_in[15];
  const float* Wff1  = (const float*)d_in[16];
  const float* bff1  = (const float*)d_in[17];
  const float* Wff2  = (const float*)d_in[18];
  const float* bff2  = (const float*)d_in[19];
  const float* g1W   = (const float*)d_in[20];
  const float* g1as  = (const float*)d_in[21];
  const float* g1ad  = (const float*)d_in[22];
  const float* g1b   = (const float*)d_in[23];
  const float* g2W   = (const float*)d_in[24];
  const float* g2as  = (const float*)d_in[25];
  const float* g2ad  = (const float*)d_in[26];
  const float* g2b   = (const float*)d_in[27];
  const float* jkW   = (const float*)d_in[28];
  const float* jkb   = (const float*)d_in[29];
  const float* Wfs   = (const float*)d_in[30];
  const float* bfs   = (const float*)d_in[31];
  const float* Wfg   = (const float*)d_in[32];
  const float* bfg   = (const float*)d_in[33];
  const int* ei      = (const int*)d_in[34];
  float* out = (float*)d_out;

  float* wf     = (float*)d_ws;
  float* dsb    = wf + DS_OFF;
  float* xg_ws  = wf + XG_OFF;
  u16*   hA     = (u16*)(wf + HA_OFF);
  u16*   hB     = (u16*)(wf + HB_OFF);
  float* hs_ws  = wf + HS_OFF;
  float* hd_ws  = wf + HD_OFF;
  int*   indptr = (int*)(wf + INT_OFF);
  int*   srcs   = indptr + 260;
  float* mS     = wf + MS_OFF;

  const size_t need = (size_t)(O_SEP_OFF + TOK_*C_) * 4;
  const bool sep = ws_size >= need;                     // deterministic (fixed per session)
  float* o_ws = sep ? (wf + O_SEP_OFF) : (wf + HA_OFF); // fallback aliases hA

  k_pre     <<<dim3(641),  dim3(256), 0, stream>>>(query, g1W, g1as, g1ad, hA, hs_ws, hd_ws,
                                                   DSm, Wemb, bemb, dsb, ei, indptr, srcs);
  k_agg1stat<<<dim3(1152), dim3(256), 0, stream>>>(hA, hs_ws, hd_ws, indptr, srcs, g1b, hB,
                                                   query, key, Wq, Wk, dsb, mS);
  k_lin2    <<<dim3(576),  dim3(256), 0, stream>>>(hB, g2W, g2as, g2ad, hA, hs_ws, hd_ws);
  if (sep){
    k_agg2av<<<dim3(1152), dim3(256), 0, stream>>>(hA, hs_ws, hd_ws, indptr, srcs, g2b, hB,
                                                   jkW, jkb, xg_ws,
                                                   query, key, value, Wq, Wk, Wv, dsb, mS, o_ws, 0);
  } else {
    k_agg2av<<<dim3(576),  dim3(256), 0, stream>>>(hA, hs_ws, hd_ws, indptr, srcs, g2b, hB,
                                                   jkW, jkb, xg_ws,
                                                   query, key, value, Wq, Wk, Wv, dsb, mS, o_ws, 0);
    k_agg2av<<<dim3(576),  dim3(256), 0, stream>>>(hA, hs_ws, hd_ws, indptr, srcs, g2b, hB,
                                                   jkW, jkb, xg_ws,
                                                   query, key, value, Wq, Wk, Wv, dsb, mS, o_ws, 576);
  }
  k_final   <<<dim3(576),  dim3(256), 0, stream>>>(query, dsb, o_ws, xg_ws,
      Wfc, bfc, ln1g, ln1b, ln2g, ln2b,
      Wff1, bff1, Wff2, bff2,
      Wfs, bfs, Wfg, bfg, out);
}

// Round 13
// 279.957 us; speedup vs baseline: 1.1293x; 1.1293x over previous
//
#include <hip/hip_runtime.h>

typedef unsigned short u16;
typedef unsigned int u32;

#define B_ 4
#define N_ 256
#define T_ 36
#define C_ 64
#define H_ 4
#define D_ 16
#define CH_ 128
#define E_ 4096
#define EQ_ 1408   // per-quarter edge cap (mean 1024, sigma ~28 -> +14 sigma)
#define G_ (B_*T_)
#define TOK_ (B_*N_*T_)

// workspace layout (float offsets)
#define DS_OFF  0
#define XG_OFF  (DS_OFF + N_*C_)
#define HA_OFF  (XG_OFF + TOK_*C_)          // bf16 h buffer A (conv outs)
#define HB_OFF  (HA_OFF + G_*N_*CH_/2)      // bf16 buffer B (h1)
#define HS_OFF  (HB_OFF + G_*N_*CH_/2)
#define HD_OFF  (HS_OFF + G_*N_)
#define INT_OFF (HD_OFF + G_*N_)
#define MS_OFF  (INT_OFF + 4608)            // (m, 1/S) pairs: 576 * 512 floats
#define O_SEP_OFF (MS_OFF + 576*512)        // separate o_ws region (if ws permits)

__device__ __forceinline__ float bf2f(u16 u){
  u32 x = ((u32)u) << 16;
  return __builtin_bit_cast(float, x);
}
__device__ __forceinline__ u16 f2bf(float f){
  u32 x = __builtin_bit_cast(u32, f);
  x += 0x7fffu + ((x >> 16) & 1u);
  return (u16)(x >> 16);
}
__device__ __forceinline__ void unpack8(uint4 u, float* f){
  f[0]=bf2f((u16)(u.x & 0xffffu)); f[1]=bf2f((u16)(u.x >> 16));
  f[2]=bf2f((u16)(u.y & 0xffffu)); f[3]=bf2f((u16)(u.y >> 16));
  f[4]=bf2f((u16)(u.z & 0xffffu)); f[5]=bf2f((u16)(u.z >> 16));
  f[6]=bf2f((u16)(u.w & 0xffffu)); f[7]=bf2f((u16)(u.w >> 16));
}
__device__ __forceinline__ uint4 pack8f(const float* f){
  uint4 u;
  u.x = (u32)f2bf(f[0]) | ((u32)f2bf(f[1]) << 16);
  u.y = (u32)f2bf(f[2]) | ((u32)f2bf(f[3]) << 16);
  u.z = (u32)f2bf(f[4]) | ((u32)f2bf(f[5]) << 16);
  u.w = (u32)f2bf(f[6]) | ((u32)f2bf(f[7]) << 16);
  return u;
}
__device__ __forceinline__ int rfl(int v){ return __builtin_amdgcn_readfirstlane(v); }

// XCD swizzle: all 4 quarter-blocks of graph g share bid%8 == g%8 (same XCD L2)
__device__ __forceinline__ void gq_from_bid(int bid, int& g, int& q){
  int xc = bid & 7, slot = bid >> 3;
  q = slot & 3;
  g = xc + ((slot >> 2) << 3);
}

#define SP_ 20   // f32 attn row pitch (80B, 16B-aligned)

// parallel per-dst edge softmax: 4 threads per dst (slices mod 4), shfl-combined.
__device__ __forceinline__ void edge_softmax_par(int tid, int n0,
    const int* __restrict__ indptr, int p00,
    const int* srcs_l, const float* hs_l, const float* __restrict__ hd_ws,
    int g, float* alpha_l)
{
  const int ld = tid >> 2;
  const int sl = tid & 3;
  const int dst = n0 + ld;
  const int p0 = indptr[dst] - p00, p1 = indptr[dst+1] - p00;
  const float hdn = hd_ws[g*N_ + dst];
  float m = -1e30f;
  for (int j = p0 + sl; j < p1; j += 4){
    float e = hs_l[srcs_l[j]] + hdn;
    e = e > 0.f ? e : 0.2f * e;
    alpha_l[j] = e;
    m = fmaxf(m, e);
  }
  m = fmaxf(m, __shfl_xor(m, 1, 64));
  m = fmaxf(m, __shfl_xor(m, 2, 64));
  float s = 0.f;
  for (int j = p0 + sl; j < p1; j += 4){
    float w = __expf(alpha_l[j] - m);
    alpha_l[j] = w; s += w;
  }
  s += __shfl_xor(s, 1, 64);
  s += __shfl_xor(s, 2, 64);
  float inv = 1.f / (s + 1e-16f);
  for (int j = p0 + sl; j < p1; j += 4) alpha_l[j] *= inv;
}

// ---------------- fused pre: lin1 (576) + ds (64) + csr (1) ----------------
__global__ __launch_bounds__(256)
void k_pre(const float* __restrict__ query, const float* __restrict__ W1,
           const float* __restrict__ as1, const float* __restrict__ ad1,
           u16* __restrict__ h, float* __restrict__ hs_ws, float* __restrict__ hd_ws,
           const float* __restrict__ DSm, const float* __restrict__ Wemb,
           const float* __restrict__ bemb, float* __restrict__ dsb,
           const int* __restrict__ ei, int* __restrict__ indptr, int* __restrict__ srcs)
{
  __shared__ union UP {
    struct { float xs[64][65]; float red[2][4][64]; } lin;
    struct { int srcL[E_]; int dstL[E_]; int tmp[E_]; int cnt[N_]; int base[N_+1]; } c;
  } S;
  const int bid = blockIdx.x;
  const int tid = threadIdx.x;

  if (bid < 576){
    int g, q; gq_from_bid(bid, g, q);
    const int n0 = q * 64;
    const int b = g / T_, t = g % T_;
    {
      const size_t gb = (((size_t)b*N_ + n0)*T_ + t)*C_;
      #pragma unroll
      for (int it = 0; it < 4; it++){
        int idx = tid + 256*it;
        int row = idx >> 4, c4 = (idx & 15) * 4;
        float4 v = *(const float4*)(query + gb + (size_t)row*(T_*C_) + c4);
        S.lin.xs[row][c4+0] = v.x; S.lin.xs[row][c4+1] = v.y;
        S.lin.xs[row][c4+2] = v.z; S.lin.xs[row][c4+3] = v.w;
      }
    }
    __syncthreads();

    const int r = tid & 63;
    const int cb = rfl(tid >> 6);
    const int ch0 = cb * 32;

    float acc[32];
    #pragma unroll
    for (int j = 0; j < 32; j++) acc[j] = 0.f;
    for (int k = 0; k < 64; k++){
      float xv = S.lin.xs[r][k];
      const float* wrow = W1 + k*CH_ + ch0;   // wave-uniform -> scalar loads
      #pragma unroll
      for (int j = 0; j < 32; j++) acc[j] += xv * wrow[j];
    }
    float hs = 0.f, hd = 0.f;
    #pragma unroll
    for (int j = 0; j < 32; j++){ hs += acc[j]*as1[ch0+j]; hd += acc[j]*ad1[ch0+j]; }
    S.lin.red[0][cb][r] = hs; S.lin.red[1][cb][r] = hd;

    u16* hp = h + ((size_t)(g*N_ + n0 + r))*CH_ + ch0;
    #pragma unroll
    for (int j8 = 0; j8 < 32; j8 += 8)
      *(uint4*)(hp + j8) = pack8f(&acc[j8]);

    __syncthreads();
    if (tid < 64){
      float a = S.lin.red[0][0][tid]+S.lin.red[0][1][tid]+S.lin.red[0][2][tid]+S.lin.red[0][3][tid];
      float d = S.lin.red[1][0][tid]+S.lin.red[1][1][tid]+S.lin.red[1][2][tid]+S.lin.red[1][3][tid];
      hs_ws[g*N_ + n0 + tid] = a;
      hd_ws[g*N_ + n0 + tid] = d;
    }
  } else if (bid < 640){
    const int n = (bid - 576) * 4 + (tid >> 6);   // wave-uniform
    const int c = tid & 63;
    float acc = bemb[c];
    for (int m = 0; m < N_; m++) acc += DSm[n*N_ + m] * Wemb[m*C_ + c];
    dsb[n*C_ + c] = acc;
  } else {
    for (int e = tid; e < E_; e += 256){ S.c.srcL[e] = ei[e]; S.c.dstL[e] = ei[E_ + e]; }
    S.c.cnt[tid] = 0;
    __syncthreads();
    for (int e = tid; e < E_; e += 256) atomicAdd(&S.c.cnt[S.c.dstL[e]], 1);
    __syncthreads();
    if (tid == 0){
      int run = 0;
      for (int i = 0; i < N_; i++){ S.c.base[i] = run; run += S.c.cnt[i]; }
      S.c.base[N_] = run;
    }
    __syncthreads();
    S.c.cnt[tid] = 0;
    __syncthreads();
    for (int e = tid; e < E_; e += 256){
      int d = S.c.dstL[e];
      int p = atomicAdd(&S.c.cnt[d], 1);
      S.c.tmp[S.c.base[d] + p] = e;
    }
    __syncthreads();
    {
      const int p0 = S.c.base[tid], p1 = S.c.base[tid] + S.c.cnt[tid];
      for (int i = p0 + 1; i < p1; i++){      // insertion sort by edge id -> deterministic
        int v = S.c.tmp[i]; int j = i - 1;
        while (j >= p0 && S.c.tmp[j] > v){ S.c.tmp[j+1] = S.c.tmp[j]; j--; }
        S.c.tmp[j+1] = v;
      }
      for (int j = p0; j < p1; j++) srcs[j] = S.c.srcL[S.c.tmp[j]];
    }
    indptr[tid] = S.c.base[tid];
    if (tid == 0) indptr[N_] = S.c.base[N_];
  }
}

// ---------------- K2: agg1 (blocks 0..575) ∥ attn stats (576..1151) ----------------
__global__ __launch_bounds__(256)
void k_agg1stat(const u16* __restrict__ hin, const float* __restrict__ hs_ws, const float* __restrict__ hd_ws,
                const int* __restrict__ indptr, const int* __restrict__ srcs,
                const float* __restrict__ bias, u16* __restrict__ hout,
                const float* __restrict__ query, const float* __restrict__ key,
                const float* __restrict__ Wq, const float* __restrict__ Wk,
                const float* __restrict__ dsb, float* __restrict__ mS)
{
  __shared__ union UA {
    struct { int srcs_l[EQ_]; float alpha_l[EQ_]; float hs_l[N_]; } a;
    struct { float qs[N_][SP_]; float wq[16][16]; float wk[16][16]; } s;
  } U;
  const int bid = blockIdx.x;
  const int tid = threadIdx.x;

  if (bid < 576){
    int g, q; gq_from_bid(bid, g, q);
    const int n0 = q * 64;

    const int p00 = indptr[n0];
    const int pend = indptr[n0 + 64];
    const int cntE = pend - p00;
    for (int i = tid; i < cntE; i += 256) U.a.srcs_l[i] = srcs[p00 + i];
    U.a.hs_l[tid] = hs_ws[g*N_ + tid];
    __syncthreads();

    edge_softmax_par(tid, n0, indptr, p00, U.a.srcs_l, U.a.hs_l, hd_ws, g, U.a.alpha_l);
    __syncthreads();

    const int r = tid & 63;
    const int cb = rfl(tid >> 6);
    const int ch0 = cb * 32;
    const int dst = n0 + r;
    const int p0 = indptr[dst] - p00, p1 = indptr[dst+1] - p00;

    float acc[32];
    #pragma unroll
    for (int j = 0; j < 32; j++) acc[j] = 0.f;
    for (int j = p0; j < p1; j++){
      float a = U.a.alpha_l[j];
      int s = U.a.srcs_l[j];
      const uint4* hp = (const uint4*)(hin + ((size_t)(g*N_ + s))*CH_ + ch0);
      #pragma unroll
      for (int qq = 0; qq < 4; qq++){
        float hv[8]; unpack8(hp[qq], hv);
        #pragma unroll
        for (int i = 0; i < 8; i++) acc[qq*8+i] += a * hv[i];
      }
    }
    float o[32];
    #pragma unroll
    for (int j = 0; j < 32; j++){
      float v = acc[j] + bias[ch0+j];
      o[j] = v > 0.f ? v : 0.f;
    }
    u16* op = hout + ((size_t)(g*N_ + dst))*CH_ + ch0;
    #pragma unroll
    for (int j8 = 0; j8 < 32; j8 += 8)
      *(uint4*)(op + j8) = pack8f(&o[j8]);
  } else {
    // attn stats: per (b,t,h), thread = column k; (m, 1/S) over q axis
    const int sb = bid - 576;
    const int b = sb / (T_*H_);
    const int rem = sb % (T_*H_);
    const int t = rem / H_;
    const int h = rem % H_;
    const int n = tid;

    U.s.wq[n>>4][n&15] = Wq[n];
    U.s.wk[n>>4][n&15] = Wk[n];

    const size_t base = ((((size_t)b*N_ + n)*T_) + t)*C_ + h*D_;
    const float* dsp = dsb + n*C_ + h*D_;

    float x[16];
    #pragma unroll
    for (int j4 = 0; j4 < 16; j4 += 4){
      float4 a = *(const float4*)(query + base + j4);
      float4 d = *(const float4*)(dsp + j4);
      x[j4]=a.x+d.x; x[j4+1]=a.y+d.y; x[j4+2]=a.z+d.z; x[j4+3]=a.w+d.w;
    }
    __syncthreads();   // weights staged
    #pragma unroll
    for (int j = 0; j < 16; j++){
      float a = 0.f;
      #pragma unroll
      for (int i = 0; i < 16; i++) a += x[i]*U.s.wq[i][j];
      U.s.qs[n][j] = a;
    }
    float khr[16];
    #pragma unroll
    for (int j4 = 0; j4 < 16; j4 += 4){
      float4 a = *(const float4*)(key + base + j4);
      float4 d = *(const float4*)(dsp + j4);
      x[j4]=a.x+d.x; x[j4+1]=a.y+d.y; x[j4+2]=a.z+d.z; x[j4+3]=a.w+d.w;
    }
    #pragma unroll
    for (int j = 0; j < 16; j++){
      float a = 0.f;
      #pragma unroll
      for (int i = 0; i < 16; i++) a += x[i]*U.s.wk[i][j];
      khr[j] = a;
    }
    __syncthreads();   // qs complete

    float m[4], s[4];
    #pragma unroll
    for (int c = 0; c < 4; c++){ m[c] = -1e30f; s[c] = 0.f; }
    for (int qq = 0; qq < 64; qq++){
      #pragma unroll
      for (int c = 0; c < 4; c++){
        const float* qrow = &U.s.qs[qq + 64*c][0];
        float4 a0 = *(const float4*)(qrow);
        float4 a1 = *(const float4*)(qrow+4);
        float4 a2 = *(const float4*)(qrow+8);
        float4 a3 = *(const float4*)(qrow+12);
        float d = a0.x*khr[0]+a0.y*khr[1]+a0.z*khr[2]+a0.w*khr[3]
                + a1.x*khr[4]+a1.y*khr[5]+a1.z*khr[6]+a1.w*khr[7]
                + a2.x*khr[8]+a2.y*khr[9]+a2.z*khr[10]+a2.w*khr[11]
                + a3.x*khr[12]+a3.y*khr[13]+a3.z*khr[14]+a3.w*khr[15];
        d *= 0.125f;
        float mn = fmaxf(m[c], d);
        s[c] = s[c]*__expf(m[c]-mn) + __expf(d-mn);
        m[c] = mn;
      }
    }
    float M = fmaxf(fmaxf(m[0],m[1]), fmaxf(m[2],m[3]));
    float S = s[0]*__expf(m[0]-M) + s[1]*__expf(m[1]-M)
            + s[2]*__expf(m[2]-M) + s[3]*__expf(m[3]-M);
    mS[(size_t)sb*512 + n*2]     = M;
    mS[(size_t)sb*512 + n*2 + 1] = 1.f / S;
  }
}

// ---------------- lin2: h2 = bf16(h1 @ W2), fused hs2/hd2 ----------------
__global__ __launch_bounds__(256)
void k_lin2(const u16* __restrict__ h1, const float* __restrict__ W2,
            const float* __restrict__ as2, const float* __restrict__ ad2,
            u16* __restrict__ h2, float* __restrict__ hs_ws, float* __restrict__ hd_ws)
{
  __shared__ float xs[64][129];
  __shared__ float red[2][4][64];
  const int bid = blockIdx.x;
  int g, q; gq_from_bid(bid, g, q);
  const int n0 = q * 64;
  const int tid = threadIdx.x;

  {
    #pragma unroll
    for (int it = 0; it < 4; it++){
      int idx = tid + 256*it;
      int row = idx >> 4, c8 = (idx & 15) * 8;
      uint4 u = *(const uint4*)(h1 + ((size_t)(g*N_ + n0 + row))*CH_ + c8);
      float v[8]; unpack8(u, v);
      #pragma unroll
      for (int i = 0; i < 8; i++) xs[row][c8+i] = v[i];
    }
  }
  __syncthreads();

  const int r = tid & 63;
  const int cb = rfl(tid >> 6);
  const int ch0 = cb * 32;

  float acc[32];
  #pragma unroll
  for (int j = 0; j < 32; j++) acc[j] = 0.f;
  for (int k = 0; k < 128; k++){
    float xv = xs[r][k];
    const float* wrow = W2 + k*CH_ + ch0;
    #pragma unroll
    for (int j = 0; j < 32; j++) acc[j] += xv * wrow[j];
  }
  float hs = 0.f, hd = 0.f;
  #pragma unroll
  for (int j = 0; j < 32; j++){ hs += acc[j]*as2[ch0+j]; hd += acc[j]*ad2[ch0+j]; }
  red[0][cb][r] = hs; red[1][cb][r] = hd;

  u16* hp = h2 + ((size_t)(g*N_ + n0 + r))*CH_ + ch0;
  #pragma unroll
  for (int j8 = 0; j8 < 32; j8 += 8)
    *(uint4*)(hp + j8) = pack8f(&acc[j8]);

  __syncthreads();
  if (tid < 64){
    float a = red[0][0][tid]+red[0][1][tid]+red[0][2][tid]+red[0][3][tid];
    float d = red[1][0][tid]+red[1][1][tid]+red[1][2][tid]+red[1][3][tid];
    hs_ws[g*N_ + n0 + tid] = a;
    hd_ws[g*N_ + n0 + tid] = d;
  }
}

// ---------------- K4: agg2+jk (eff 0..575) ∥ attn AV (eff 576..1151) ----------------
__global__ __launch_bounds__(256)
void k_agg2av(const u16* __restrict__ h2, const float* __restrict__ hs_ws, const float* __restrict__ hd_ws,
              const int* __restrict__ indptr, const int* __restrict__ srcs,
              const float* __restrict__ b2, const u16* __restrict__ h1,
              const float* __restrict__ jkW, const float* __restrict__ jkb, float* __restrict__ xg,
              const float* __restrict__ query, const float* __restrict__ key, const float* __restrict__ value,
              const float* __restrict__ Wq, const float* __restrict__ Wk, const float* __restrict__ Wv,
              const float* __restrict__ dsb, const float* __restrict__ mS, float* __restrict__ o_ws,
              int bid_base)
{
  __shared__ union UJ {
    struct { int srcs_l[EQ_]; float alpha_l[EQ_]; float hs_l[N_]; } a;
    struct { u16 xs[64][136]; } l;
    struct { float ks[N_][SP_]; float vs[N_][SP_]; float2 msl[N_];
             float wq[16][16]; float wk[16][16]; float wv[16][16]; } v;
  } U;
  const int bid = blockIdx.x + bid_base;
  const int tid = threadIdx.x;

  if (bid < 576){
    int g, q; gq_from_bid(bid, g, q);
    const int n0 = q * 64;
    const int b = g / T_, t = g % T_;

    // ---- agg2 (output stays in regs) ----
    const int p00 = indptr[n0];
    const int pend = indptr[n0 + 64];
    const int cntE = pend - p00;
    for (int i = tid; i < cntE; i += 256) U.a.srcs_l[i] = srcs[p00 + i];
    U.a.hs_l[tid] = hs_ws[g*N_ + tid];
    __syncthreads();

    edge_softmax_par(tid, n0, indptr, p00, U.a.srcs_l, U.a.hs_l, hd_ws, g, U.a.alpha_l);
    __syncthreads();

    const int r = tid & 63;
    const int cb = rfl(tid >> 6);
    const int ch0 = cb * 32;
    const int dst = n0 + r;
    const int p0 = indptr[dst] - p00, p1 = indptr[dst+1] - p00;

    float acc[32];
    #pragma unroll
    for (int j = 0; j < 32; j++) acc[j] = 0.f;
    for (int j = p0; j < p1; j++){
      float a = U.a.alpha_l[j];
      int s = U.a.srcs_l[j];
      const uint4* hp = (const uint4*)(h2 + ((size_t)(g*N_ + s))*CH_ + ch0);
      #pragma unroll
      for (int qq = 0; qq < 4; qq++){
        float hv[8]; unpack8(hp[qq], hv);
        #pragma unroll
        for (int i = 0; i < 8; i++) acc[qq*8+i] += a * hv[i];
      }
    }
    float o[32];
    {
      const uint4* h1p = (const uint4*)(h1 + ((size_t)(g*N_ + dst))*CH_ + ch0);
      #pragma unroll
      for (int j8 = 0; j8 < 32; j8 += 8){
        float h1v[8]; unpack8(h1p[j8>>3], h1v);
        #pragma unroll
        for (int i = 0; i < 8; i++){
          float v = acc[j8+i] + b2[ch0+j8+i];
          v = v > 0.f ? v : 0.f;
          o[j8+i] = fmaxf(h1v[i], v);
        }
      }
    }
    __syncthreads();   // all agg reads of U.a done

    // regs -> xs (bf16)
    #pragma unroll
    for (int j8 = 0; j8 < 32; j8 += 8)
      *(uint4*)&U.l.xs[r][ch0 + j8] = pack8f(&o[j8]);
    __syncthreads();

    // jk linear: xg(time-reversed) = xs @ jkW + jkb
    const int o0 = cb * 16;
    float acc2[16];
    #pragma unroll
    for (int j = 0; j < 16; j++) acc2[j] = 0.f;
    for (int k8 = 0; k8 < 16; k8++){
      uint4 u = *(const uint4*)&U.l.xs[r][k8*8];
      float hv[8]; unpack8(u, hv);
      #pragma unroll
      for (int kk = 0; kk < 8; kk++){
        const float* wrow = jkW + (k8*8+kk)*C_ + o0;
        #pragma unroll
        for (int j = 0; j < 16; j++) acc2[j] += hv[kk] * wrow[j];
      }
    }
    float* op = xg + ((((size_t)b*N_ + n0 + r)*T_) + (T_-1-t))*C_ + o0;
    #pragma unroll
    for (int j4 = 0; j4 < 16; j4 += 4){
      float4 v = make_float4(acc2[j4]+jkb[o0+j4], acc2[j4+1]+jkb[o0+j4+1],
                             acc2[j4+2]+jkb[o0+j4+2], acc2[j4+3]+jkb[o0+j4+3]);
      *(float4*)(op + j4) = v;
    }
  } else {
    // ---- attn AV: per (b,t,h), thread = row q; stats precomputed ----
    const int sb = bid - 576;
    const int b = sb / (T_*H_);
    const int rem = sb % (T_*H_);
    const int t = rem / H_;
    const int h = rem % H_;
    const int n = tid;

    U.v.wq[n>>4][n&15] = Wq[n];
    U.v.wk[n>>4][n&15] = Wk[n];
    U.v.wv[n>>4][n&15] = Wv[n];
    U.v.msl[n] = *(const float2*)(mS + (size_t)sb*512 + n*2);

    const size_t base = ((((size_t)b*N_ + n)*T_) + t)*C_ + h*D_;
    const float* dsp = dsb + n*C_ + h*D_;

    float ds16[16];
    #pragma unroll
    for (int j4 = 0; j4 < 16; j4 += 4){
      float4 d = *(const float4*)(dsp + j4);
      ds16[j4]=d.x; ds16[j4+1]=d.y; ds16[j4+2]=d.z; ds16[j4+3]=d.w;
    }
    __syncthreads();   // weights staged

    float x[16];
    #pragma unroll
    for (int j4 = 0; j4 < 16; j4 += 4){
      float4 a = *(const float4*)(key + base + j4);
      x[j4]=a.x+ds16[j4]; x[j4+1]=a.y+ds16[j4+1]; x[j4+2]=a.z+ds16[j4+2]; x[j4+3]=a.w+ds16[j4+3];
    }
    #pragma unroll
    for (int j = 0; j < 16; j++){
      float a = 0.f;
      #pragma unroll
      for (int i = 0; i < 16; i++) a += x[i]*U.v.wk[i][j];
      U.v.ks[n][j] = a;
    }
    #pragma unroll
    for (int j4 = 0; j4 < 16; j4 += 4){
      float4 a = *(const float4*)(value + base + j4);
      x[j4]=a.x+ds16[j4]; x[j4+1]=a.y+ds16[j4+1]; x[j4+2]=a.z+ds16[j4+2]; x[j4+3]=a.w+ds16[j4+3];
    }
    #pragma unroll
    for (int j = 0; j < 16; j++){
      float a = 0.f;
      #pragma unroll
      for (int i = 0; i < 16; i++) a += x[i]*U.v.wv[i][j];
      U.v.vs[n][j] = a;
    }
    float qhr[16];
    #pragma unroll
    for (int j4 = 0; j4 < 16; j4 += 4){
      float4 a = *(const float4*)(query + base + j4);
      x[j4]=a.x+ds16[j4]; x[j4+1]=a.y+ds16[j4+1]; x[j4+2]=a.z+ds16[j4+2]; x[j4+3]=a.w+ds16[j4+3];
    }
    #pragma unroll
    for (int j = 0; j < 16; j++){
      float a = 0.f;
      #pragma unroll
      for (int i = 0; i < 16; i++) a += x[i]*U.v.wq[i][j];
      qhr[j] = a;
    }
    __syncthreads();   // ks/vs/msl complete

    float o0[16], o1[16];
    #pragma unroll
    for (int j = 0; j < 16; j++){ o0[j] = 0.f; o1[j] = 0.f; }
    for (int k = 0; k < N_; k += 2){
      {
        const float* krow = &U.v.ks[k][0];
        float4 a0 = *(const float4*)(krow);
        float4 a1 = *(const float4*)(krow+4);
        float4 a2 = *(const float4*)(krow+8);
        float4 a3 = *(const float4*)(krow+12);
        float d = a0.x*qhr[0]+a0.y*qhr[1]+a0.z*qhr[2]+a0.w*qhr[3]
                + a1.x*qhr[4]+a1.y*qhr[5]+a1.z*qhr[6]+a1.w*qhr[7]
                + a2.x*qhr[8]+a2.y*qhr[9]+a2.z*qhr[10]+a2.w*qhr[11]
                + a3.x*qhr[12]+a3.y*qhr[13]+a3.z*qhr[14]+a3.w*qhr[15];
        float2 ms0 = U.v.msl[k];
        float p = __expf(d*0.125f - ms0.x) * ms0.y;
        const float* vrow = &U.v.vs[k][0];
        float4 v0 = *(const float4*)(vrow);
        float4 v1 = *(const float4*)(vrow+4);
        float4 v2 = *(const float4*)(vrow+8);
        float4 v3 = *(const float4*)(vrow+12);
        o0[0]+=p*v0.x; o0[1]+=p*v0.y; o0[2]+=p*v0.z; o0[3]+=p*v0.w;
        o0[4]+=p*v1.x; o0[5]+=p*v1.y; o0[6]+=p*v1.z; o0[7]+=p*v1.w;
        o0[8]+=p*v2.x; o0[9]+=p*v2.y; o0[10]+=p*v2.z; o0[11]+=p*v2.w;
        o0[12]+=p*v3.x; o0[13]+=p*v3.y; o0[14]+=p*v3.z; o0[15]+=p*v3.w;
      }
      {
        const float* krow = &U.v.ks[k+1][0];
        float4 a0 = *(const float4*)(krow);
        float4 a1 = *(const float4*)(krow+4);
        float4 a2 = *(const float4*)(krow+8);
        float4 a3 = *(const float4*)(krow+12);
        float d = a0.x*qhr[0]+a0.y*qhr[1]+a0.z*qhr[2]+a0.w*qhr[3]
                + a1.x*qhr[4]+a1.y*qhr[5]+a1.z*qhr[6]+a1.w*qhr[7]
                + a2.x*qhr[8]+a2.y*qhr[9]+a2.z*qhr[10]+a2.w*qhr[11]
                + a3.x*qhr[12]+a3.y*qhr[13]+a3.z*qhr[14]+a3.w*qhr[15];
        float2 ms1 = U.v.msl[k+1];
        float p = __expf(d*0.125f - ms1.x) * ms1.y;
        const float* vrow = &U.v.vs[k+1][0];
        float4 v0 = *(const float4*)(vrow);
        float4 v1 = *(const float4*)(vrow+4);
        float4 v2 = *(const float4*)(vrow+8);
        float4 v3 = *(const float4*)(vrow+12);
        o1[0]+=p*v0.x; o1[1]+=p*v0.y; o1[2]+=p*v0.z; o1[3]+=p*v0.w;
        o1[4]+=p*v1.x; o1[5]+=p*v1.y; o1[6]+=p*v1.z; o1[7]+=p*v1.w;
        o1[8]+=p*v2.x; o1[9]+=p*v2.y; o1[10]+=p*v2.z; o1[11]+=p*v2.w;
        o1[12]+=p*v3.x; o1[13]+=p*v3.y; o1[14]+=p*v3.z; o1[15]+=p*v3.w;
      }
    }
    float* op = o_ws + base;
    #pragma unroll
    for (int j4 = 0; j4 < 16; j4 += 4)
      *(float4*)(op + j4) = make_float4(o0[j4]+o1[j4], o0[j4+1]+o1[j4+1],
                                        o0[j4+2]+o1[j4+2], o0[j4+3]+o1[j4+3]);
  }
}

// ---------------- fused epilogue: bf16 LDS staging ----------------
__global__ __launch_bounds__(256)
void k_final(const float* __restrict__ query, const float* __restrict__ dsb,
             const float* __restrict__ o_ws, const float* __restrict__ xg_ws,
             const float* __restrict__ Wfc, const float* __restrict__ bfc,
             const float* __restrict__ ln1g, const float* __restrict__ ln1b,
             const float* __restrict__ ln2g, const float* __restrict__ ln2b,
             const float* __restrict__ Wff1, const float* __restrict__ bff1,
             const float* __restrict__ Wff2, const float* __restrict__ bff2,
             const float* __restrict__ Wfs, const float* __restrict__ bfs,
             const float* __restrict__ Wfg, const float* __restrict__ bfg,
             float* __restrict__ out)
{
  __shared__ u16 smA[64*66];                       // o_t -> us_t (bf16)
  __shared__ u16 smB[64*66];                       // qd_t -> ms_t (bf16)
  __shared__ union UH { u16 h[128*66]; float o[64*66]; } HH;  // hidden/xg (bf16) -> out_t (f32)
  __shared__ float lnxA[4][64];
  __shared__ float lnxB[4][64];

  const int tid = threadIdx.x;
  const int token0 = blockIdx.x * 64;
  const int w = rfl(tid >> 6);
  const int tok = tid & 63;
  const int c0 = w * 16;

  #pragma unroll
  for (int it = 0; it < 4; it++){
    int idx = tid + 256*it;
    int tk = idx >> 4, c4 = (idx & 15) * 4;
    int gtok = token0 + tk;
    int n = (gtok / T_) & (N_-1);
    float4 ov = *(const float4*)(o_ws + (size_t)gtok*C_ + c4);
    float4 qv = *(const float4*)(query + (size_t)gtok*C_ + c4);
    float4 dv = *(const float4*)(dsb + n*C_ + c4);
    smA[(c4+0)*66+tk] = f2bf(ov.x); smA[(c4+1)*66+tk] = f2bf(ov.y);
    smA[(c4+2)*66+tk] = f2bf(ov.z); smA[(c4+3)*66+tk] = f2bf(ov.w);
    smB[(c4+0)*66+tk] = f2bf(qv.x+dv.x); smB[(c4+1)*66+tk] = f2bf(qv.y+dv.y);
    smB[(c4+2)*66+tk] = f2bf(qv.z+dv.z); smB[(c4+3)*66+tk] = f2bf(qv.w+dv.w);
  }
  __syncthreads();

  // fc
  float x1[16];
  #pragma unroll
  for (int j = 0; j < 16; j++) x1[j] = 0.f;
  for (int i = 0; i < C_; i++){
    float ov = bf2f(smA[i*66 + tok]);
    const float* wrow = Wfc + i*C_ + c0;
    #pragma unroll
    for (int j = 0; j < 16; j++) x1[j] += ov * wrow[j];
  }
  #pragma unroll
  for (int j = 0; j < 16; j++) x1[j] += bfc[c0+j] + bf2f(smB[(c0+j)*66 + tok]);

  // LN1
  float s1 = 0.f;
  #pragma unroll
  for (int j = 0; j < 16; j++) s1 += x1[j];
  lnxA[w][tok] = s1;
  __syncthreads();
  float mu = (lnxA[0][tok]+lnxA[1][tok]+lnxA[2][tok]+lnxA[3][tok]) * (1.f/64.f);
  float v1 = 0.f;
  #pragma unroll
  for (int j = 0; j < 16; j++){ float d = x1[j]-mu; v1 += d*d; }
  lnxB[w][tok] = v1;
  __syncthreads();
  float var = (lnxB[0][tok]+lnxB[1][tok]+lnxB[2][tok]+lnxB[3][tok]) * (1.f/64.f);
  float rstd = rsqrtf(var + 1e-5f);
  float ms[16];
  #pragma unroll
  for (int j = 0; j < 16; j++) ms[j] = (x1[j]-mu)*rstd*ln1g[c0+j] + ln1b[c0+j];
  __syncthreads();
  #pragma unroll
  for (int j = 0; j < 16; j++) smB[(c0+j)*66 + tok] = f2bf(ms[j]);
  __syncthreads();

  // FFN
  float part[16];
  #pragma unroll
  for (int j = 0; j < 16; j++) part[j] = 0.f;
  #pragma unroll
  for (int ch = 0; ch < 2; ch++){
    float fch[32];
    #pragma unroll
    for (int kk = 0; kk < 32; kk++) fch[kk] = 0.f;
    const int kbase = w*64 + ch*32;
    for (int i = 0; i < C_; i++){
      float msv = bf2f(smB[i*66 + tok]);
      const float* wrow = Wff1 + i*(4*C_) + kbase;
      #pragma unroll
      for (int kk = 0; kk < 32; kk++) fch[kk] += msv * wrow[kk];
    }
    #pragma unroll
    for (int kk = 0; kk < 32; kk++){
      float v = fch[kk] + bff1[kbase+kk];
      fch[kk] = v > 0.f ? v : 0.f;
    }
    if (ch) __syncthreads();
    #pragma unroll
    for (int kk = 0; kk < 32; kk++) HH.h[(w*32+kk)*66 + tok] = f2bf(fch[kk]);
    __syncthreads();
    #pragma unroll
    for (int wq = 0; wq < 4; wq++){
      #pragma unroll 8
      for (int kk = 0; kk < 32; kk++){
        int k = wq*64 + ch*32 + kk;
        float hv = bf2f(HH.h[(wq*32+kk)*66 + tok]);
        const float* wrow = Wff2 + k*C_ + c0;
        #pragma unroll
        for (int j = 0; j < 16; j++) part[j] += hv * wrow[j];
      }
    }
  }
  float x2[16];
  #pragma unroll
  for (int j = 0; j < 16; j++) x2[j] = part[j] + bff2[c0+j] + ms[j];

  // LN2
  float s2 = 0.f;
  #pragma unroll
  for (int j = 0; j < 16; j++) s2 += x2[j];
  __syncthreads();
  lnxA[w][tok] = s2;
  __syncthreads();
  float mu2 = (lnxA[0][tok]+lnxA[1][tok]+lnxA[2][tok]+lnxA[3][tok]) * (1.f/64.f);
  float v2 = 0.f;
  #pragma unroll
  for (int j = 0; j < 16; j++){ float d = x2[j]-mu2; v2 += d*d; }
  lnxB[w][tok] = v2;
  __syncthreads();
  float var2 = (lnxB[0][tok]+lnxB[1][tok]+lnxB[2][tok]+lnxB[3][tok]) * (1.f/64.f);
  float rstd2 = rsqrtf(var2 + 1e-5f);
  float us[16];
  #pragma unroll
  for (int j = 0; j < 16; j++) us[j] = (x2[j]-mu2)*rstd2*ln2g[c0+j] + ln2b[c0+j];

  // us -> smA ; xg -> HH.h rows 0..63 (hidden dead)
  #pragma unroll
  for (int j = 0; j < 16; j++) smA[(c0+j)*66 + tok] = f2bf(us[j]);
  #pragma unroll
  for (int it = 0; it < 4; it++){
    int idx = tid + 256*it;
    int tk = idx >> 4, c4 = (idx & 15) * 4;
    int gtok = token0 + tk;
    float4 xv = *(const float4*)(xg_ws + (size_t)gtok*C_ + c4);
    HH.h[(c4+0)*66+tk] = f2bf(xv.x); HH.h[(c4+1)*66+tk] = f2bf(xv.y);
    HH.h[(c4+2)*66+tk] = f2bf(xv.z); HH.h[(c4+3)*66+tk] = f2bf(xv.w);
  }
  __syncthreads();

  // gate
  float ga[16];
  #pragma unroll
  for (int j = 0; j < 16; j++) ga[j] = 0.f;
  for (int i = 0; i < C_; i++){
    float uv = bf2f(smA[i*66 + tok]);
    float xv = bf2f(HH.h[i*66 + tok]);
    const float* wsr = Wfs + i*C_ + c0;
    const float* wgr = Wfg + i*C_ + c0;
    #pragma unroll
    for (int j = 0; j < 16; j++) ga[j] += uv*wsr[j] + xv*wgr[j];
  }
  float res[16];
  #pragma unroll
  for (int j = 0; j < 16; j++){
    float a = ga[j] + bfs[c0+j] + bfg[c0+j];
    float gg = 1.f / (1.f + __expf(-a));
    float xgv = bf2f(HH.h[(c0+j)*66 + tok]);
    res[j] = gg*us[j] + (1.f-gg)*xgv;
  }
  __syncthreads();   // all xg reads done before f32 reuse of HH
  #pragma unroll
  for (int j = 0; j < 16; j++) HH.o[(c0+j)*66 + tok] = res[j];
  __syncthreads();
  #pragma unroll
  for (int it = 0; it < 4; it++){
    int idx = tid + 256*it;
    int tk = idx >> 4, c4 = (idx & 15) * 4;
    int gtok = token0 + tk;
    float4 v = make_float4(HH.o[(c4+0)*66+tk], HH.o[(c4+1)*66+tk],
                           HH.o[(c4+2)*66+tk], HH.o[(c4+3)*66+tk]);
    *(float4*)(out + (size_t)gtok*C_ + c4) = v;
  }
}

extern "C" void kernel_launch(void* const* d_in, const int* in_sizes, int n_in,
                              void* d_out, int out_size, void* d_ws, size_t ws_size,
                              hipStream_t stream)
{
  (void)in_sizes; (void)n_in; (void)out_size;
  const float* query = (const float*)d_in[0];
  const float* key   = (const float*)d_in[1];
  const float* value = (const float*)d_in[2];
  const float* DSm   = (const float*)d_in[4];
  const float* Wemb  = (const float*)d_in[5];
  const float* bemb  = (const float*)d_in[6];
  const float* Wq    = (const float*)d_in[7];
  const float* Wk    = (const float*)d_in[8];
  const float* Wv    = (const float*)d_in[9];
  const float* Wfc   = (const float*)d_in[10];
  const float* bfc   = (const float*)d_in[11];
  const float* ln1g  = (const float*)d_in[12];
  const float* ln1b  = (const float*)d_in[13];
  const float* ln2g  = (const float*)d_in[14];
  const float* ln2b  = (const float*)d_in[15];
  const float* Wff1  = (const float*)d_in[16];
  const float* bff1  = (const float*)d_in[17];
  const float* Wff2  = (const float*)d_in[18];
  const float* bff2  = (const float*)d_in[19];
  const float* g1W   = (const float*)d_in[20];
  const float* g1as  = (const float*)d_in[21];
  const float* g1ad  = (const float*)d_in[22];
  const float* g1b   = (const float*)d_in[23];
  const float* g2W   = (const float*)d_in[24];
  const float* g2as  = (const float*)d_in[25];
  const float* g2ad  = (const float*)d_in[26];
  const float* g2b   = (const float*)d_in[27];
  const float* jkW   = (const float*)d_in[28];
  const float* jkb   = (const float*)d_in[29];
  const float* Wfs   = (const float*)d_in[30];
  const float* bfs   = (const float*)d_in[31];
  const float* Wfg   = (const float*)d_in[32];
  const float* bfg   = (const float*)d_in[33];
  const int* ei      = (const int*)d_in[34];
  float* out = (float*)d_out;

  float* wf     = (float*)d_ws;
  float* dsb    = wf + DS_OFF;
  float* xg_ws  = wf + XG_OFF;
  u16*   hA     = (u16*)(wf + HA_OFF);
  u16*   hB     = (u16*)(wf + HB_OFF);
  float* hs_ws  = wf + HS_OFF;
  float* hd_ws  = wf + HD_OFF;
  int*   indptr = (int*)(wf + INT_OFF);
  int*   srcs   = indptr + 260;
  float* mS     = wf + MS_OFF;

  const size_t need = (size_t)(O_SEP_OFF + TOK_*C_) * 4;
  const bool sep = ws_size >= need;                     // deterministic (fixed per session)
  float* o_ws = sep ? (wf + O_SEP_OFF) : (wf + HA_OFF); // fallback aliases hA

  k_pre     <<<dim3(641),  dim3(256), 0, stream>>>(query, g1W, g1as, g1ad, hA, hs_ws, hd_ws,
                                                   DSm, Wemb, bemb, dsb, ei, indptr, srcs);
  k_agg1stat<<<dim3(1152), dim3(256), 0, stream>>>(hA, hs_ws, hd_ws, indptr, srcs, g1b, hB,
                                                   query, key, Wq, Wk, dsb, mS);
  k_lin2    <<<dim3(576),  dim3(256), 0, stream>>>(hB, g2W, g2as, g2ad, hA, hs_ws, hd_ws);
  if (sep){
    k_agg2av<<<dim3(1152), dim3(256), 0, stream>>>(hA, hs_ws, hd_ws, indptr, srcs, g2b, hB,
                                                   jkW, jkb, xg_ws,
                                                   query, key, value, Wq, Wk, Wv, dsb, mS, o_ws, 0);
  } else {
    k_agg2av<<<dim3(576),  dim3(256), 0, stream>>>(hA, hs_ws, hd_ws, indptr, srcs, g2b, hB,
                                                   jkW, jkb, xg_ws,
                                                   query, key, value, Wq, Wk, Wv, dsb, mS, o_ws, 0);
    k_agg2av<<<dim3(576),  dim3(256), 0, stream>>>(hA, hs_ws, hd_ws, indptr, srcs, g2b, hB,
                                                   jkW, jkb, xg_ws,
                                                   query, key, value, Wq, Wk, Wv, dsb, mS, o_ws, 576);
  }
  k_final   <<<dim3(576),  dim3(256), 0, stream>>>(query, dsb, o_ws, xg_ws,
      Wfc, bfc, ln1g, ln1b, ln2g, ln2b,
      Wff1, bff1, Wff2, bff2,
      Wfs, bfs, Wfg, bfg, out);
}